// Round 9
// baseline (34.714 us; speedup 1.0000x reference)
//
#include <hip/hip_runtime.h>
#include <math.h>

// Hausdorff distance, X[8192,3] vs Y[8192,3] fp32 — ONE pair kernel, no reduce
// pipeline. d2(i,j) = |a_i|^2 - 2*max_j(a_i . b_j - |b_j|^2/2).
// 1024 blocks = 2 dirs x 512; each block owns 16 rows x ALL 8192 cols:
//   - 16 rows staged to LDS (48 floats), packed into v2f registers
//   - each thread streams 32 cols from global (L2-resident, 12B-stride coalesced)
//   - inner loop: 3 v_pk_fma + 1 v_pk_max per 2 pairs (2 instr/pair)
//   - per-row min via wave shfl_xor butterfly + tiny LDS cross-wave merge
//   - one atomicMax(uint bits) per block -> out (memset to 0 first)
// No inter-block reduction, no ws usage, 2 dispatches total (memset + kernel).

typedef float v2f __attribute__((ext_vector_type(2)));

constexpr int NPTS = 8192;
constexpr int T = 256;            // threads per block (4 waves)
constexpr int RPB = 16;           // rows per block
constexpr int BPD = NPTS / RPB;   // 512 blocks per direction
constexpr int NBLK = 2 * BPD;     // 1024 blocks
constexpr int CPT = NPTS / T;     // 32 cols per thread

__global__ __launch_bounds__(T) void hausdorff_onepass_kernel(
        const float* __restrict__ X, const float* __restrict__ Y,
        unsigned* __restrict__ outbits) {
    int b = blockIdx.x;
    int dir = (b >= BPD) ? 1 : 0;
    int rb = (b - dir * BPD) * RPB;          // first row of this block
    const float* A = dir ? Y : X;
    const float* B = dir ? X : Y;
    int t = threadIdx.x;

    __shared__ float As[RPB * 3];            // 16 rows x (x,y,z)
    __shared__ float tmax[T / 64][RPB];      // per-wave row maxima
    if (t < RPB * 3) As[t] = A[rb * 3 + t];
    __syncthreads();

    // rows -> packed registers (same values in every thread; LDS broadcast)
    v2f ax2[RPB / 2], ay2[RPB / 2], az2[RPB / 2], mt2[RPB / 2];
#pragma unroll
    for (int q = 0; q < RPB / 2; ++q) {
        ax2[q] = (v2f){As[(2 * q) * 3 + 0], As[(2 * q + 1) * 3 + 0]};
        ay2[q] = (v2f){As[(2 * q) * 3 + 1], As[(2 * q + 1) * 3 + 1]};
        az2[q] = (v2f){As[(2 * q) * 3 + 2], As[(2 * q + 1) * 3 + 2]};
        mt2[q] = (v2f){-__builtin_inff(), -__builtin_inff()};
    }

    // stream 32 cols per thread; consecutive lanes -> consecutive cols (12B apart)
#pragma unroll 4
    for (int i = 0; i < CPT; ++i) {
        int j = i * T + t;
        float bx = B[j * 3 + 0], by = B[j * 3 + 1], bz = B[j * 3 + 2];
        float c = -0.5f * fmaf(bx, bx, fmaf(by, by, bz * bz));
        v2f px = (v2f){bx, bx};
        v2f py = (v2f){by, by};
        v2f pz = (v2f){bz, bz};
        v2f pw = (v2f){c, c};
#pragma unroll
        for (int q = 0; q < RPB / 2; ++q) {
            v2f tt = az2[q] * pz + pw;       // fp-contract -> v_pk_fma_f32
            tt = ay2[q] * py + tt;
            tt = ax2[q] * px + tt;
            mt2[q] = __builtin_elementwise_max(mt2[q], tt);
        }
    }

    // wave-level butterfly max over 64 lanes (all lanes share the same rows)
#pragma unroll
    for (int o = 32; o > 0; o >>= 1) {
#pragma unroll
        for (int q = 0; q < RPB / 2; ++q) {
            v2f s;
            s.x = __shfl_xor(mt2[q].x, o);
            s.y = __shfl_xor(mt2[q].y, o);
            mt2[q] = __builtin_elementwise_max(mt2[q], s);
        }
    }

    // lane 0 of each wave publishes its 16 row-maxima (static indexing only)
    int lane = t & 63, w = t >> 6;
    if (lane == 0) {
#pragma unroll
        for (int q = 0; q < RPB / 2; ++q) {
            tmax[w][2 * q]     = mt2[q].x;
            tmax[w][2 * q + 1] = mt2[q].y;
        }
    }
    __syncthreads();

    // wave 0: merge 4 waves, d2 per row, max over rows, sqrt, one atomic
    if (t < 64) {
        float d2 = 0.f;
        if (t < RPB) {
            float m = fmaxf(fmaxf(tmax[0][t], tmax[1][t]),
                            fmaxf(tmax[2][t], tmax[3][t]));
            float ax = As[t * 3 + 0], ay = As[t * 3 + 1], az = As[t * 3 + 2];
            float na = fmaf(ax, ax, fmaf(ay, ay, az * az));
            d2 = fmaxf(fmaf(-2.f, m, na), 0.f);  // clamp tiny negatives
        }
#pragma unroll
        for (int o = 8; o > 0; o >>= 1) d2 = fmaxf(d2, __shfl_down(d2, o));
        if (t == 0)
            atomicMax(outbits, __float_as_uint(sqrtf(d2)));
    }
}

extern "C" void kernel_launch(void* const* d_in, const int* in_sizes, int n_in,
                              void* d_out, int out_size, void* d_ws, size_t ws_size,
                              hipStream_t stream) {
    const float* X = (const float*)d_in[0];
    const float* Y = (const float*)d_in[1];
    unsigned* outbits = (unsigned*)d_out;

    // out = 0.0f (non-negative float bits order as unsigned -> atomicMax exact)
    hipMemsetAsync(outbits, 0, sizeof(unsigned), stream);
    hausdorff_onepass_kernel<<<NBLK, T, 0, stream>>>(X, Y, outbits);
}

// Round 10
// 28.485 us; speedup vs baseline: 1.2187x; 1.2187x over previous
//
#include <hip/hip_runtime.h>
#include <math.h>

// Hausdorff distance, X[8192,3] vs Y[8192,3] fp32.
// d2(i,j) = |a_i|^2 - 2*max_term, max_term = max_j (a_i . b_j - |b_j|^2/2).
// 2 dispatches, no memset, no contended atomics:
//  K1 pair<256,4,32>: 512 blocks (2/CU), per-(row,colchunk) min via packed
//     fp32 FMA on LDS float4 broadcast; block 0 zeroes the K2 counter.
//  K2 reduce_final: 256 blocks x 64 thr, 1 row/thread, 32 strided loads;
//     per-block row-max -> blockmax; last block (counter election) does the
//     256-way max + sqrt -> out.

typedef float v2f __attribute__((ext_vector_type(2)));

constexpr int NPTS = 8192;
constexpr int T = 256;             // K1 threads per block
constexpr int R = 4;               // K1 rows per thread (2 float2 groups)
constexpr int ROWS_PB = T * R;     // 1024
constexpr int RG = NPTS / ROWS_PB; // 8 row groups
constexpr int CG = 32;             // col chunks per direction
constexpr int COLS = NPTS / CG;    // 256 B-points per K1 block

constexpr int RT = 64;                  // K2 threads per block
constexpr int RBLK = 2 * NPTS / RT;     // 256 K2 blocks

__global__ __launch_bounds__(T) void pair_partial_kernel(
        const float* __restrict__ X, const float* __restrict__ Y,
        float* __restrict__ partial, unsigned* __restrict__ counter) {
    int b = blockIdx.x;
    if (b == 0 && threadIdx.x == 0) *counter = 0u;  // for K2 (next dispatch)
    int dir = b / (RG * CG);
    int rem = b - dir * (RG * CG);
    int rg = rem / CG;
    int cg = rem - rg * CG;
    const float* A = dir ? Y : X;
    const float* B = dir ? X : Y;

    int t = threadIdx.x;
    int r0 = rg * ROWS_PB + t;

    // A rows -> packed registers (issued early; latency hides under staging)
    v2f ax2[R / 2], ay2[R / 2], az2[R / 2], na2[R / 2], mt2[R / 2];
#pragma unroll
    for (int q = 0; q < R / 2; ++q) {
        int ra = r0 + (2 * q) * T;
        int rb = r0 + (2 * q + 1) * T;
        ax2[q] = (v2f){A[ra * 3 + 0], A[rb * 3 + 0]};
        ay2[q] = (v2f){A[ra * 3 + 1], A[rb * 3 + 1]};
        az2[q] = (v2f){A[ra * 3 + 2], A[rb * 3 + 2]};
    }

    // Stage B chunk as (x, y, z, -0.5*|b|^2)
    __shared__ float4 Bs[COLS];
    for (int i = t; i < COLS; i += T) {
        int j = cg * COLS + i;
        float bx = B[j * 3 + 0], by = B[j * 3 + 1], bz = B[j * 3 + 2];
        Bs[i] = make_float4(bx, by, bz, -0.5f * fmaf(bx, bx, fmaf(by, by, bz * bz)));
    }

#pragma unroll
    for (int q = 0; q < R / 2; ++q) {
        na2[q] = ax2[q] * ax2[q] + ay2[q] * ay2[q] + az2[q] * az2[q];
        mt2[q] = (v2f){-__builtin_inff(), -__builtin_inff()};
    }
    __syncthreads();

#pragma unroll 8
    for (int j = 0; j < COLS; ++j) {
        float4 p = Bs[j];  // wave-uniform -> ds_read_b128 broadcast, 0 conflicts
        v2f px = (v2f){p.x, p.x};
        v2f py = (v2f){p.y, p.y};
        v2f pz = (v2f){p.z, p.z};
        v2f pw = (v2f){p.w, p.w};
#pragma unroll
        for (int q = 0; q < R / 2; ++q) {
            v2f tt = az2[q] * pz + pw;   // fp-contract -> v_pk_fma_f32
            tt = ay2[q] * py + tt;
            tt = ax2[q] * px + tt;
            mt2[q] = __builtin_elementwise_max(mt2[q], tt);  // v_pk_max_f32
        }
    }

    // partial d2-min for this col chunk; coalesced stores
    float* op = partial + (size_t)(dir * CG + cg) * NPTS + rg * ROWS_PB + t;
#pragma unroll
    for (int q = 0; q < R / 2; ++q) {
        op[(2 * q) * T]     = fmaf(-2.f, mt2[q].x, na2[q].x);
        op[(2 * q + 1) * T] = fmaf(-2.f, mt2[q].y, na2[q].y);
    }
}

__global__ __launch_bounds__(RT) void reduce_final_kernel(
        const float* __restrict__ partial, float* __restrict__ blockmax,
        unsigned* __restrict__ counter, float* __restrict__ out) {
    int rid = blockIdx.x * RT + threadIdx.x;  // 0..16383
    int dir = rid >> 13;
    int row = rid & (NPTS - 1);
    const float* p = partial + (size_t)dir * CG * NPTS + row;

    // 32 independent strided loads, 8 accumulators -> deep VMEM pipelining
    float m[8];
#pragma unroll
    for (int k = 0; k < 8; ++k) m[k] = __builtin_inff();
#pragma unroll
    for (int cg = 0; cg < CG; ++cg)
        m[cg & 7] = fminf(m[cg & 7], p[(size_t)cg * NPTS]);
#pragma unroll
    for (int k = 0; k < 4; ++k) m[k] = fminf(m[k], m[k + 4]);
    float mm = fmaxf(fminf(fminf(m[0], m[1]), fminf(m[2], m[3])), 0.f);

    // wave butterfly max (block = one wave)
#pragma unroll
    for (int o = 32; o > 0; o >>= 1) mm = fmaxf(mm, __shfl_xor(mm, o));
    if (threadIdx.x == 0)
        __hip_atomic_store(&blockmax[blockIdx.x], mm, __ATOMIC_RELEASE,
                           __HIP_MEMORY_SCOPE_AGENT);

    // last-block election (256 single-address atomics total — benign)
    __shared__ unsigned is_last;
    if (threadIdx.x == 0)
        is_last = (__hip_atomic_fetch_add(counter, 1u, __ATOMIC_ACQ_REL,
                                          __HIP_MEMORY_SCOPE_AGENT) == RBLK - 1);
    __syncthreads();
    if (!is_last) return;

    float bm = 0.f;
#pragma unroll
    for (int k = 0; k < RBLK / RT; ++k) {
        float v = __hip_atomic_load(&blockmax[k * RT + threadIdx.x],
                                    __ATOMIC_ACQUIRE, __HIP_MEMORY_SCOPE_AGENT);
        bm = fmaxf(bm, v);
    }
#pragma unroll
    for (int o = 32; o > 0; o >>= 1) bm = fmaxf(bm, __shfl_xor(bm, o));
    if (threadIdx.x == 0) out[0] = sqrtf(bm);
}

// ---------- last-resort fallback (tiny ws): atomic version ----------

__global__ void init_min_kernel(unsigned* wsmin, int n) {
    int i = blockIdx.x * blockDim.x + threadIdx.x;
    if (i < n) wsmin[i] = 0x7F800000u;
}

__global__ __launch_bounds__(256) void pair_min_kernel(
        const float* __restrict__ X, const float* __restrict__ Y,
        unsigned* __restrict__ minXY, unsigned* __restrict__ minYX) {
    constexpr int SEG_J = 512;
    constexpr int SEGS = NPTS / SEG_J;
    constexpr int RPB8 = 256 * 8;
    constexpr int BLOCKS_PER_DIR = (NPTS / RPB8) * SEGS;
    int b = blockIdx.x;
    int dir = b / BLOCKS_PER_DIR;
    int rem = b - dir * BLOCKS_PER_DIR;
    int rg = rem / SEGS;
    int seg = rem - rg * SEGS;
    const float* A = dir ? Y : X;
    const float* B = dir ? X : Y;
    unsigned* omin = dir ? minYX : minXY;

    __shared__ float Bs[SEG_J * 3];
    int t = threadIdx.x;
    const float* Bseg = B + seg * SEG_J * 3;
    for (int i = t; i < SEG_J * 3; i += 256) Bs[i] = Bseg[i];

    int r0 = rg * RPB8 + t;
    float ax[8], ay[8], az[8], m[8];
#pragma unroll
    for (int r = 0; r < 8; ++r) {
        int row = r0 + r * 256;
        ax[r] = A[row * 3 + 0];
        ay[r] = A[row * 3 + 1];
        az[r] = A[row * 3 + 2];
        m[r] = __builtin_inff();
    }
    __syncthreads();

#pragma unroll 2
    for (int j = 0; j < SEG_J; ++j) {
        float bx = Bs[3 * j + 0], by = Bs[3 * j + 1], bz = Bs[3 * j + 2];
#pragma unroll
        for (int r = 0; r < 8; ++r) {
            float dx = ax[r] - bx, dy = ay[r] - by, dz = az[r] - bz;
            m[r] = fminf(m[r], fmaf(dx, dx, fmaf(dy, dy, dz * dz)));
        }
    }
#pragma unroll
    for (int r = 0; r < 8; ++r)
        atomicMin(&omin[r0 + r * 256], __float_as_uint(m[r]));
}

__global__ __launch_bounds__(256) void finalize_min_kernel(
        const unsigned* __restrict__ wsmin, float* __restrict__ out, int n) {
    int t = threadIdx.x;
    float mx = 0.f;
    for (int i = t; i < n; i += 256) mx = fmaxf(mx, __uint_as_float(wsmin[i]));
    for (int o = 32; o > 0; o >>= 1) mx = fmaxf(mx, __shfl_down(mx, o));
    __shared__ float wmax[4];
    if ((t & 63) == 0) wmax[t >> 6] = mx;
    __syncthreads();
    if (t == 0) {
        float mm = fmaxf(fmaxf(wmax[0], wmax[1]), fmaxf(wmax[2], wmax[3]));
        out[0] = sqrtf(mm);
    }
}

extern "C" void kernel_launch(void* const* d_in, const int* in_sizes, int n_in,
                              void* d_out, int out_size, void* d_ws, size_t ws_size,
                              hipStream_t stream) {
    const float* X = (const float*)d_in[0];
    const float* Y = (const float*)d_in[1];
    float* out = (float*)d_out;

    const size_t partial_elems = (size_t)2 * CG * NPTS;
    const size_t need = (partial_elems + RBLK + 1) * sizeof(float);

    if (ws_size >= need) {
        float* partial = (float*)d_ws;
        float* blockmax = partial + partial_elems;
        unsigned* counter = (unsigned*)(blockmax + RBLK);
        pair_partial_kernel<<<2 * RG * CG, T, 0, stream>>>(X, Y, partial, counter);
        reduce_final_kernel<<<RBLK, RT, 0, stream>>>(partial, blockmax, counter, out);
    } else if (ws_size >= 2 * NPTS * sizeof(unsigned)) {
        unsigned* wsmin = (unsigned*)d_ws;
        init_min_kernel<<<(2 * NPTS + 255) / 256, 256, 0, stream>>>(wsmin, 2 * NPTS);
        pair_min_kernel<<<2 * (NPTS / (256 * 8)) * (NPTS / 512), 256, 0, stream>>>(
            X, Y, wsmin, wsmin + NPTS);
        finalize_min_kernel<<<1, 256, 0, stream>>>(wsmin, out, 2 * NPTS);
    }
}

// Round 11
// 27.370 us; speedup vs baseline: 1.2683x; 1.0408x over previous
//
#include <hip/hip_runtime.h>
#include <math.h>

// Hausdorff distance, X[8192,3] vs Y[8192,3] fp32 — MFMA version.
// d2(i,j) = |a_i|^2 - 2*s(i,j),  s = a.b - |b|^2/2, computed as a K=11 dot
// product on the matrix pipe via hi/lo bf16 splitting (error ~3e-4 in d2):
//   A'[i,:] = [ha0,ha1,ha2, ha0,ha1,ha2, la0,la1,la2, 1, 1, 0...]   (K=16)
//   B'[j,:] = [hb0,hb1,hb2, lb0,lb1,lb2, hb0,hb1,hb2, ch, cl, 0...]
//   sum_k A'[i,k]B'[j,k] = ha.hb + ha.lb + la.hb + ch + cl ~= a.b - |b|^2/2
// One v_mfma_f32_32x32x16_bf16 per 32x32 tile; per-score cost = 1 fmax.
// Pipeline: prep (pack) -> main (512 blk: 32 rows x all cols, final d2/row,
// no inter-block reduce) -> final (1 blk max+sqrt).

typedef __attribute__((ext_vector_type(8))) short bf16x8;
typedef __attribute__((ext_vector_type(16))) float f32x16;
typedef __attribute__((ext_vector_type(4))) unsigned uint4v;

constexpr int NPTS = 8192;

static __device__ __forceinline__ unsigned short f2bf_rn(float x) {
    unsigned u = __float_as_uint(x);
    unsigned r = u + 0x7FFFu + ((u >> 16) & 1u);
    return (unsigned short)(r >> 16);
}

// Pack X and Y into A-pattern and B-pattern rows (16 bf16 each).
// Apack rows: [X ; Y] (dir0 rows = X, dir1 rows = Y).
// Bpack rows: [Y ; X] (dir0 cols = Y, dir1 cols = X)  -> slot = i ^ NPTS.
__global__ __launch_bounds__(256) void prep_kernel(
        const float* __restrict__ X, const float* __restrict__ Y,
        unsigned short* __restrict__ Apack, unsigned short* __restrict__ Bpack) {
    int i = blockIdx.x * 256 + threadIdx.x;  // 0..16383
    const float* src = (i < NPTS) ? (X + (size_t)i * 3) : (Y + (size_t)(i - NPTS) * 3);
    float x0 = src[0], x1 = src[1], x2 = src[2];

    unsigned short h0 = f2bf_rn(x0), h1 = f2bf_rn(x1), h2 = f2bf_rn(x2);
    float hf0 = __uint_as_float((unsigned)h0 << 16);
    float hf1 = __uint_as_float((unsigned)h1 << 16);
    float hf2 = __uint_as_float((unsigned)h2 << 16);
    unsigned short l0 = f2bf_rn(x0 - hf0);
    unsigned short l1 = f2bf_rn(x1 - hf1);
    unsigned short l2 = f2bf_rn(x2 - hf2);

    float c = -0.5f * fmaf(x0, x0, fmaf(x1, x1, x2 * x2));
    unsigned short ch = f2bf_rn(c);
    float chf = __uint_as_float((unsigned)ch << 16);
    unsigned short cl = f2bf_rn(c - chf);

    const unsigned short ONE = 0x3F80;
    alignas(16) unsigned short a[16] = {h0, h1, h2, h0, h1, h2, l0, l1,
                                        l2, ONE, ONE, 0, 0, 0, 0, 0};
    alignas(16) unsigned short bb[16] = {h0, h1, h2, l0, l1, l2, h0, h1,
                                         h2, ch, cl, 0, 0, 0, 0, 0};

    unsigned short* ap = Apack + (size_t)i * 16;
    unsigned short* bp = Bpack + (size_t)(i ^ NPTS) * 16;
    *(uint4v*)(ap)     = *(const uint4v*)(a);
    *(uint4v*)(ap + 8) = *(const uint4v*)(a + 8);
    *(uint4v*)(bp)     = *(const uint4v*)(bb);
    *(uint4v*)(bp + 8) = *(const uint4v*)(bb + 8);
}

// 512 blocks x 256 thr (4 waves). Block: dir = b>>8, rows = (b&255)*32 .. +32.
// Wave w covers cols w*2048 .. +2048 (64 col-tiles of 32).
// A-frag fixed per wave; B-frag one 16B global load per tile (L2-resident).
// C/D layout (HW-verified): col = lane&31, row = (reg&3) + 8*(reg>>2) + 4*(lane>>5).
__global__ __launch_bounds__(256) void mfma_main_kernel(
        const float* __restrict__ X, const float* __restrict__ Y,
        const unsigned short* __restrict__ Apack,
        const unsigned short* __restrict__ Bpack,
        float* __restrict__ d2buf) {
    int b = blockIdx.x;
    int dir = b >> 8;
    int row0 = (b & 255) * 32;
    int t = threadIdx.x;
    int w = t >> 6, l = t & 63;
    int lhalf = l >> 5, lmod = l & 31;

    // A-frag: lane l holds A'[row0+lmod][lhalf*8 .. +8]
    bf16x8 af = *(const bf16x8*)(Apack +
        ((size_t)(dir * NPTS + row0 + lmod) * 16 + lhalf * 8));

    const unsigned short* Bbase = Bpack +
        ((size_t)(dir * NPTS + w * 2048 + lmod) * 16 + lhalf * 8);

    f32x16 rmax;
#pragma unroll
    for (int r = 0; r < 16; ++r) rmax[r] = -__builtin_inff();
    f32x16 zacc;
#pragma unroll
    for (int r = 0; r < 16; ++r) zacc[r] = 0.f;

#pragma unroll 2
    for (int tile = 0; tile < 64; ++tile) {
        bf16x8 bf = *(const bf16x8*)(Bbase + (size_t)tile * 32 * 16);
        f32x16 d = __builtin_amdgcn_mfma_f32_32x32x16_bf16(af, bf, zacc, 0, 0, 0);
#pragma unroll
        for (int r = 0; r < 16; ++r) rmax[r] = fmaxf(rmax[r], d[r]);
    }

    // max over the 32 col-residues (lanes within each 32-half share rows)
#pragma unroll
    for (int o = 1; o <= 16; o <<= 1) {
#pragma unroll
        for (int r = 0; r < 16; ++r)
            rmax[r] = fmaxf(rmax[r], __shfl_xor(rmax[r], o));
    }

    __shared__ float rmaxs[4][32];
    if (lmod == 0) {
#pragma unroll
        for (int r = 0; r < 16; ++r)
            rmaxs[w][(r & 3) + 8 * (r >> 2) + 4 * lhalf] = rmax[r];
    }
    __syncthreads();

    if (t < 32) {
        float m = fmaxf(fmaxf(rmaxs[0][t], rmaxs[1][t]),
                        fmaxf(rmaxs[2][t], rmaxs[3][t]));
        int row = row0 + t;
        const float* A = dir ? Y : X;
        float a0 = A[(size_t)row * 3 + 0];
        float a1 = A[(size_t)row * 3 + 1];
        float a2 = A[(size_t)row * 3 + 2];
        float na = fmaf(a0, a0, fmaf(a1, a1, a2 * a2));
        d2buf[dir * NPTS + row] = fmaxf(fmaf(-2.f, m, na), 0.f);
    }
}

__global__ __launch_bounds__(1024) void final_kernel(
        const float* __restrict__ d2buf, float* __restrict__ out) {
    int t = threadIdx.x;
    float m = 0.f;
#pragma unroll
    for (int k = 0; k < 2 * NPTS / 1024; ++k)
        m = fmaxf(m, d2buf[k * 1024 + t]);
#pragma unroll
    for (int o = 32; o > 0; o >>= 1) m = fmaxf(m, __shfl_xor(m, o));
    __shared__ float wm[16];
    if ((t & 63) == 0) wm[t >> 6] = m;
    __syncthreads();
    if (t == 0) {
        float mm = wm[0];
#pragma unroll
        for (int v = 1; v < 16; ++v) mm = fmaxf(mm, wm[v]);
        out[0] = sqrtf(mm);
    }
}

// ---------- last-resort fallback (tiny ws): proven atomic path ----------

__global__ void init_min_kernel(unsigned* wsmin, int n) {
    int i = blockIdx.x * blockDim.x + threadIdx.x;
    if (i < n) wsmin[i] = 0x7F800000u;
}

__global__ __launch_bounds__(256) void pair_min_kernel(
        const float* __restrict__ X, const float* __restrict__ Y,
        unsigned* __restrict__ minXY, unsigned* __restrict__ minYX) {
    constexpr int SEG_J = 512;
    constexpr int SEGS = NPTS / SEG_J;
    constexpr int RPB8 = 256 * 8;
    constexpr int BLOCKS_PER_DIR = (NPTS / RPB8) * SEGS;
    int b = blockIdx.x;
    int dir = b / BLOCKS_PER_DIR;
    int rem = b - dir * BLOCKS_PER_DIR;
    int rg = rem / SEGS;
    int seg = rem - rg * SEGS;
    const float* A = dir ? Y : X;
    const float* B = dir ? X : Y;
    unsigned* omin = dir ? minYX : minXY;

    __shared__ float Bs[SEG_J * 3];
    int t = threadIdx.x;
    const float* Bseg = B + seg * SEG_J * 3;
    for (int i = t; i < SEG_J * 3; i += 256) Bs[i] = Bseg[i];

    int r0 = rg * RPB8 + t;
    float ax[8], ay[8], az[8], m[8];
#pragma unroll
    for (int r = 0; r < 8; ++r) {
        int row = r0 + r * 256;
        ax[r] = A[row * 3 + 0];
        ay[r] = A[row * 3 + 1];
        az[r] = A[row * 3 + 2];
        m[r] = __builtin_inff();
    }
    __syncthreads();

#pragma unroll 2
    for (int j = 0; j < SEG_J; ++j) {
        float bx = Bs[3 * j + 0], by = Bs[3 * j + 1], bz = Bs[3 * j + 2];
#pragma unroll
        for (int r = 0; r < 8; ++r) {
            float dx = ax[r] - bx, dy = ay[r] - by, dz = az[r] - bz;
            m[r] = fminf(m[r], fmaf(dx, dx, fmaf(dy, dy, dz * dz)));
        }
    }
#pragma unroll
    for (int r = 0; r < 8; ++r)
        atomicMin(&omin[r0 + r * 256], __float_as_uint(m[r]));
}

__global__ __launch_bounds__(256) void finalize_min_kernel(
        const unsigned* __restrict__ wsmin, float* __restrict__ out, int n) {
    int t = threadIdx.x;
    float mx = 0.f;
    for (int i = t; i < n; i += 256) mx = fmaxf(mx, __uint_as_float(wsmin[i]));
    for (int o = 32; o > 0; o >>= 1) mx = fmaxf(mx, __shfl_down(mx, o));
    __shared__ float wmax[4];
    if ((t & 63) == 0) wmax[t >> 6] = mx;
    __syncthreads();
    if (t == 0) {
        float mm = fmaxf(fmaxf(wmax[0], wmax[1]), fmaxf(wmax[2], wmax[3]));
        out[0] = sqrtf(mm);
    }
}

extern "C" void kernel_launch(void* const* d_in, const int* in_sizes, int n_in,
                              void* d_out, int out_size, void* d_ws, size_t ws_size,
                              hipStream_t stream) {
    const float* X = (const float*)d_in[0];
    const float* Y = (const float*)d_in[1];
    float* out = (float*)d_out;

    const size_t pack_elems = (size_t)2 * NPTS * 16;          // per array, ushort
    const size_t apack_b = pack_elems * sizeof(unsigned short); // 512 KB
    const size_t need = 2 * apack_b + (size_t)2 * NPTS * sizeof(float) + 256;

    if (ws_size >= need) {
        unsigned short* Apack = (unsigned short*)d_ws;
        unsigned short* Bpack = Apack + pack_elems;
        float* d2buf = (float*)(Bpack + pack_elems);
        prep_kernel<<<2 * NPTS / 256, 256, 0, stream>>>(X, Y, Apack, Bpack);
        mfma_main_kernel<<<512, 256, 0, stream>>>(X, Y, Apack, Bpack, d2buf);
        final_kernel<<<1, 1024, 0, stream>>>(d2buf, out);
    } else if (ws_size >= 2 * NPTS * sizeof(unsigned)) {
        unsigned* wsmin = (unsigned*)d_ws;
        init_min_kernel<<<(2 * NPTS + 255) / 256, 256, 0, stream>>>(wsmin, 2 * NPTS);
        pair_min_kernel<<<2 * (NPTS / (256 * 8)) * (NPTS / 512), 256, 0, stream>>>(
            X, Y, wsmin, wsmin + NPTS);
        finalize_min_kernel<<<1, 256, 0, stream>>>(wsmin, out, 2 * NPTS);
    }
}